// Round 5
// baseline (16337.173 us; speedup 1.0000x reference)
//
#include <hip/hip_runtime.h>

#define H_  1024
#define B_  8
#define T_  2048
#define V_  256
#define NWG 256
#define NTH 256

typedef unsigned long long u64;

__device__ __forceinline__ u64 agload64(const u64* p) {
  return __hip_atomic_load(p, __ATOMIC_RELAXED, __HIP_MEMORY_SCOPE_AGENT);
}
__device__ __forceinline__ void agstore64(u64* p, u64 v) {
  __hip_atomic_store(p, v, __ATOMIC_RELAXED, __HIP_MEMORY_SCOPE_AGENT);
}
__device__ __forceinline__ unsigned f2bf(float f) {   // 16-bit bf16, RNE
  unsigned u = __builtin_bit_cast(unsigned, f);
  return (u + 0x7fffu + ((u >> 16) & 1u)) >> 16;
}
__device__ __forceinline__ float bf2f(unsigned hw) {
  return __builtin_bit_cast(float, hw << 16);
}

__global__ __launch_bounds__(NTH, 1)
void charrnn_lstm(const int* __restrict__ Xs, const int* __restrict__ ys,
                  const float* __restrict__ W_ih, const float* __restrict__ W_hh,
                  const float* __restrict__ b_ih, const float* __restrict__ b_hh,
                  const float* __restrict__ W1, const float* __restrict__ b1,
                  float* __restrict__ out, u64* __restrict__ hg64)
{
  // LDS ~56 KB (<64KB). W_hh slice in 128 VGPRs/thread (2 rows x 16 float4).
  __shared__ float hstage[B_][H_];
  __shared__ float Wis[16][V_];
  __shared__ float stash[H_];
  __shared__ float logits_s[V_];
  __shared__ float gates_s[16][8];
  __shared__ float c_s[4][8];
  __shared__ float bias_s[16];
  __shared__ int   xw[8][32];      // 32-step window of Xs

  const int wg   = blockIdx.x;
  const int tid  = threadIdx.x;
  const int b_g  = wg & 7;    // batch whose loss this WG computes
  const int slot = wg >> 3;   // t%32 slot this WG stashes
  const int seg  = tid & 15;        // k-segment 0..15
  const int bh   = (tid >> 4) & 1;  // batch half 0..1
  const int rp   = tid >> 5;        // row pair 0..7 (rows 2rp, 2rp+1)

  // ---- W_hh row-pair slice -> registers (each h4 load reused across 2 rows) ----
  const int r0 = rp * 2, r1 = r0 + 1;
  const int rg0 = (r0 >> 2) * H_ + wg * 4 + (r0 & 3);
  const int rg1 = (r1 >> 2) * H_ + wg * 4 + (r1 & 3);
  float4 wreg[2][16];
  #pragma unroll
  for (int q = 0; q < 16; ++q) {
    wreg[0][q] = *(const float4*)&W_hh[(size_t)rg0 * H_ + seg * 4 + q * 64];
    wreg[1][q] = *(const float4*)&W_hh[(size_t)rg1 * H_ + seg * 4 + q * 64];
  }

  // ---- one-time staging of W_ih slice into LDS ----
  for (int i = tid; i < 16 * (V_ / 4); i += NTH) {
    int rl = i >> 6;
    int kq = i & 63;
    int rr = (rl >> 2) * H_ + wg * 4 + (rl & 3);
    *(float4*)&Wis[rl][kq * 4] = *(const float4*)&W_ih[(size_t)rr * V_ + kq * 4];
  }
  if (tid < 16) {
    int rr = (tid >> 2) * H_ + wg * 4 + (tid & 3);
    bias_s[tid] = b_ih[rr] + b_hh[rr];
  }
  if (tid < 32) c_s[tid >> 3][tid & 7] = 0.f;

  int   pending = 0, chunk = 0, ptau = 0;
  float wg_loss = 0.f;

  auto do_chunk = [&]() {   // 1/32 slice of output-projection + CE for (b_g, ptau)
    const int v_loc = tid >> 5, lane32 = tid & 31;
    const int vg = chunk * 8 + v_loc;
    const float* wrow = &W1[(size_t)vg * H_];
    float4 la = make_float4(0.f, 0.f, 0.f, 0.f);
    #pragma unroll
    for (int j = 0; j < 8; ++j) {
      const int k0 = lane32 * 4 + j * 128;
      const float4 w4 = *(const float4*)&wrow[k0];
      const float4 h4 = *(const float4*)&stash[k0];
      la.x = fmaf(w4.x, h4.x, la.x);
      la.y = fmaf(w4.y, h4.y, la.y);
      la.z = fmaf(w4.z, h4.z, la.z);
      la.w = fmaf(w4.w, h4.w, la.w);
    }
    float l = (la.x + la.y) + (la.z + la.w);
    #pragma unroll
    for (int m = 1; m < 32; m <<= 1) l += __shfl_xor(l, m, 64);
    if (lane32 == 0) logits_s[vg] = l + b1[vg];
    chunk++;
    if (chunk == 32) {
      __syncthreads();
      if (tid < 64) {
        float mx = -3.4e38f;
        #pragma unroll
        for (int i2 = 0; i2 < 4; ++i2) mx = fmaxf(mx, logits_s[tid * 4 + i2]);
        #pragma unroll
        for (int m = 1; m < 64; m <<= 1) mx = fmaxf(mx, __shfl_xor(mx, m, 64));
        float se = 0.f;
        #pragma unroll
        for (int i2 = 0; i2 < 4; ++i2) se += __expf(logits_s[tid * 4 + i2] - mx);
        #pragma unroll
        for (int m = 1; m < 64; m <<= 1) se += __shfl_xor(se, m, 64);
        if (tid == 0) {
          const float ly = logits_s[ys[b_g * T_ + ptau]];
          wg_loss += -(ly - mx - __logf(se));
        }
      }
      pending = 0;
      chunk = 0;
      __syncthreads();
    }
  };

  __syncthreads();

  for (int t = 0; t < T_; ++t) {
    // ---- 1. tag-poll stage of h(t-1): 16 x b64 self-validating words ----
    const u64* hb = hg64 + (size_t)((t + 1) & 1) * (B_ * H_ / 2);
    const unsigned tag = (unsigned)t;
    u64 v[16];
    for (;;) {
      bool ok = true;
      #pragma unroll
      for (int i = 0; i < 16; ++i) v[i] = agload64(&hb[i * NTH + tid]);
      #pragma unroll
      for (int i = 0; i < 16; ++i) ok &= ((unsigned)v[i] == tag);
      if (ok) break;
      __builtin_amdgcn_s_sleep(1);
    }
    #pragma unroll
    for (int i = 0; i < 16; ++i) {
      const int idx = i * NTH + tid;          // word index; 512 words per batch
      const int b = idx >> 9, p = idx & 511;
      *(float2*)&hstage[b][p * 2] =
          make_float2(bf2f((unsigned)(v[i] >> 32) & 0xffffu),
                      bf2f((unsigned)(v[i] >> 48)));
    }
    if ((t & 31) == 0) {   // refresh 32-step Xs window
      const int b = tid >> 5, tt = t + (tid & 31);
      xw[b][tid & 31] = (tt < T_) ? Xs[b * T_ + tt] : 0;
    }
    __syncthreads();

    // ---- 2. gate partial dots: 2 rows x 4 batches per thread, h4 reused 2x ----
    float4 acc[2][4];
    #pragma unroll
    for (int r2 = 0; r2 < 2; ++r2)
      #pragma unroll
      for (int bb = 0; bb < 4; ++bb) acc[r2][bb] = make_float4(0.f, 0.f, 0.f, 0.f);
    #pragma unroll
    for (int q = 0; q < 16; ++q) {
      const int k0 = seg * 4 + q * 64;
      float4 h4[4];
      #pragma unroll
      for (int bb = 0; bb < 4; ++bb) h4[bb] = *(const float4*)&hstage[bh * 4 + bb][k0];
      #pragma unroll
      for (int r2 = 0; r2 < 2; ++r2) {
        const float4 w = wreg[r2][q];
        #pragma unroll
        for (int bb = 0; bb < 4; ++bb) {
          acc[r2][bb].x = fmaf(w.x, h4[bb].x, acc[r2][bb].x);
          acc[r2][bb].y = fmaf(w.y, h4[bb].y, acc[r2][bb].y);
          acc[r2][bb].z = fmaf(w.z, h4[bb].z, acc[r2][bb].z);
          acc[r2][bb].w = fmaf(w.w, h4[bb].w, acc[r2][bb].w);
        }
      }
    }
    float s[2][4];
    #pragma unroll
    for (int r2 = 0; r2 < 2; ++r2)
      #pragma unroll
      for (int bb = 0; bb < 4; ++bb)
        s[r2][bb] = (acc[r2][bb].x + acc[r2][bb].y) + (acc[r2][bb].z + acc[r2][bb].w);
    #pragma unroll
    for (int m = 1; m < 16; m <<= 1) {
      #pragma unroll
      for (int r2 = 0; r2 < 2; ++r2)
        #pragma unroll
        for (int bb = 0; bb < 4; ++bb) s[r2][bb] += __shfl_xor(s[r2][bb], m, 64);
    }
    if (seg < 8) {   // 8 lanes per 16-group write the 8 reduced values
      const int r2 = seg >> 2, bb = seg & 3;
      const int r = rp * 2 + r2, b = bh * 4 + bb;
      gates_s[r][b] = s[r2][bb] + Wis[r][xw[b][t & 31]] + bias_s[r];
    }
    __syncthreads();

    // ---- 3. c/h update + paired 64-bit tagged store ----
    if (tid < 32) {
      const int jj = tid >> 3, b = tid & 7;
      float iv = gates_s[jj][b],      fv = gates_s[4 + jj][b];
      float gv = gates_s[8 + jj][b],  ov = gates_s[12 + jj][b];
      iv = 1.f / (1.f + __expf(-iv));
      fv = 1.f / (1.f + __expf(-fv));
      gv = tanhf(gv);
      ov = 1.f / (1.f + __expf(-ov));
      const float c = fv * c_s[jj][b] + iv * gv;
      c_s[jj][b] = c;
      const float h = ov * tanhf(c);
      const unsigned hb16 = f2bf(h);
      const unsigned ph = (unsigned)__shfl_xor((int)hb16, 8, 64); // partner unit
      if ((jj & 1) == 0) {
        const u64 w = ((u64)ph << 48) | ((u64)hb16 << 32) | (unsigned)(t + 1);
        agstore64(&hg64[(size_t)(t & 1) * (B_ * H_ / 2) + b * (H_ / 2)
                        + wg * 2 + (jj >> 1)], w);
      }
    }

    // ---- 4. stash h(tau) for this WG's loss position ----
    const int tau = t - 1;   // hstage holds h(t-1)
    const bool newst = (tau >= 0 && (tau & 31) == slot && !pending);
    if (newst) {
      for (int i = tid; i < H_; i += NTH) stash[i] = hstage[b_g][i];
    }
    if (newst) { pending = 1; chunk = 0; ptau = tau; }
    __syncthreads();   // stash ready; also fences hstage reuse vs next stage

    // ---- 5. fused-loss slice: hides under h-store visibility window ----
    if (pending) do_chunk();
  }

  // ---- drain in-flight loss position ----
  while (pending) do_chunk();

  // ---- tau = T-1 (slot 31): poll-decode final h for batch b_g ----
  if (slot == 31) {
    const u64* hb = hg64 + (size_t)((T_ - 1) & 1) * (B_ * H_ / 2);
    for (int k = 0; k < 2; ++k) {
      const int p = k * NTH + tid;   // 0..511
      u64 w;
      do { w = agload64(&hb[b_g * (H_ / 2) + p]); } while ((unsigned)w != (unsigned)T_);
      *(float2*)&stash[p * 2] = make_float2(bf2f((unsigned)(w >> 32) & 0xffffu),
                                            bf2f((unsigned)(w >> 48)));
    }
    pending = 1; chunk = 0; ptau = T_ - 1;
    __syncthreads();
    while (pending) do_chunk();
  }

  if (tid == 0) atomicAdd(out, wg_loss * (1.0f / (B_ * T_)));
}

extern "C" void kernel_launch(void* const* d_in, const int* in_sizes, int n_in,
                              void* d_out, int out_size, void* d_ws, size_t ws_size,
                              hipStream_t stream) {
  const int*   Xs   = (const int*)d_in[0];
  const int*   ys   = (const int*)d_in[1];
  // d_in[2] = predict (always 0)
  const float* W_ih = (const float*)d_in[3];
  const float* W_hh = (const float*)d_in[4];
  const float* b_ih = (const float*)d_in[5];
  const float* b_hh = (const float*)d_in[6];
  const float* W1   = (const float*)d_in[7];
  const float* b1   = (const float*)d_in[8];
  float* out = (float*)d_out;

  u64* hg64 = (u64*)d_ws;   // [2][B*H/2] tagged 64-bit words

  // replay-safe: zeroed buffer == h(-1)=0 with tag 0; zero loss accumulator
  hipMemsetAsync(d_out, 0, sizeof(float) * (size_t)out_size, stream);
  hipMemsetAsync(d_ws, 0, 2 * (B_ * H_ / 2) * sizeof(u64), stream);

  void* args[] = { (void*)&Xs, (void*)&ys, (void*)&W_ih, (void*)&W_hh,
                   (void*)&b_ih, (void*)&b_hh, (void*)&W1, (void*)&b1,
                   (void*)&out, (void*)&hg64 };
  hipError_t e = hipLaunchCooperativeKernel((const void*)charrnn_lstm, dim3(NWG),
                                            dim3(NTH), args, 0, stream);
  if (e != hipSuccess) {
    hipLaunchKernelGGL(charrnn_lstm, dim3(NWG), dim3(NTH), 0, stream,
                       Xs, ys, W_ih, W_hh, b_ih, b_hh, W1, b1, out, hg64);
  }
}

// Round 6
// 9308.368 us; speedup vs baseline: 1.7551x; 1.7551x over previous
//
#include <hip/hip_runtime.h>

#define H_  1024
#define B_  8
#define T_  2048
#define V_  256
#define NWG 256
#define NTH 256
#define WPS (B_ * H_ / 4)   // 2048 u64 words per slot

typedef unsigned long long u64;

__device__ __forceinline__ u64 agload64(const u64* p) {
  return __hip_atomic_load(p, __ATOMIC_RELAXED, __HIP_MEMORY_SCOPE_AGENT);
}
__device__ __forceinline__ void agstore64(u64* p, u64 v) {
  __hip_atomic_store(p, v, __ATOMIC_RELAXED, __HIP_MEMORY_SCOPE_AGENT);
}
// full-precision bf16, RNE
__device__ __forceinline__ unsigned f2bf(float f) {
  unsigned u = __builtin_bit_cast(unsigned, f);
  return (u + 0x7fffu + ((u >> 16) & 1u)) >> 16;
}
// bf16 rounded (RNE) to 4-ULP grid: 2 LSBs free for the tag
__device__ __forceinline__ unsigned f2bf14(float f) {
  unsigned u = __builtin_bit_cast(unsigned, f);
  return ((u + 0x1FFFFu + ((u >> 18) & 1u)) >> 18) << 2;
}

__global__ __launch_bounds__(NTH, 1)
void charrnn_lstm(const int* __restrict__ Xs, const int* __restrict__ ys,
                  const float* __restrict__ W_ih, const float* __restrict__ W_hh,
                  const float* __restrict__ b_ih, const float* __restrict__ b_hh,
                  const float* __restrict__ W1, const float* __restrict__ b1,
                  float* __restrict__ out, u64* __restrict__ hg64)
{
  // LDS ~56 KB (<64KB). W_hh slice in 64 VGPRs/thread (round-4 budget; R=2 spilled).
  __shared__ float hstage[B_][H_];
  __shared__ float Wis[16][V_];
  __shared__ float stash[H_];
  __shared__ float logits_s[V_];
  __shared__ float gates_s[16][8];
  __shared__ float c_s[4][8];
  __shared__ float bias_s[16];
  __shared__ int   xw[8][32];      // 32-step window of Xs

  const int wg   = blockIdx.x;
  const int tid  = threadIdx.x;
  const int b_g  = wg & 7;    // batch whose loss this WG computes
  const int slot = wg >> 3;   // t%32 slot this WG stashes
  const int row  = tid >> 4;  // 0..15 : local gate-row (gate*4 + jj)
  const int seg  = tid & 15;  // 0..15 : k-segment

  // ---- W_hh slice -> registers: thread (row,seg) needs exactly these 64 floats ----
  const int rg = (row >> 2) * H_ + wg * 4 + (row & 3);
  float4 wreg[16];
  #pragma unroll
  for (int q = 0; q < 16; ++q)
    wreg[q] = *(const float4*)&W_hh[(size_t)rg * H_ + seg * 4 + q * 64];

  // ---- one-time staging of W_ih slice into LDS ----
  for (int i = tid; i < 16 * (V_ / 4); i += NTH) {
    int rl = i >> 6;
    int kq = i & 63;
    int rr = (rl >> 2) * H_ + wg * 4 + (rl & 3);
    *(float4*)&Wis[rl][kq * 4] = *(const float4*)&W_ih[(size_t)rr * V_ + kq * 4];
  }
  if (tid < 16) {
    int rr = (tid >> 2) * H_ + wg * 4 + (tid & 3);
    bias_s[tid] = b_ih[rr] + b_hh[rr];
  }
  if (tid < 32) c_s[tid >> 3][tid & 7] = 0.f;

  int   pending = 0, chunk = 0, ptau = 0;
  float wg_loss = 0.f;

  auto do_chunk = [&]() {   // 1/32 slice of output-projection + CE for (b_g, ptau)
    const int v_loc = tid >> 5, lane32 = tid & 31;
    const int vg = chunk * 8 + v_loc;
    const float* wrow = &W1[(size_t)vg * H_];
    float4 la = make_float4(0.f, 0.f, 0.f, 0.f);
    #pragma unroll
    for (int j = 0; j < 8; ++j) {
      const int k0 = lane32 * 4 + j * 128;
      const float4 w4 = *(const float4*)&wrow[k0];
      const float4 h4 = *(const float4*)&stash[k0];
      la.x = fmaf(w4.x, h4.x, la.x);
      la.y = fmaf(w4.y, h4.y, la.y);
      la.z = fmaf(w4.z, h4.z, la.z);
      la.w = fmaf(w4.w, h4.w, la.w);
    }
    float l = (la.x + la.y) + (la.z + la.w);
    #pragma unroll
    for (int m = 1; m < 32; m <<= 1) l += __shfl_xor(l, m, 64);
    if (lane32 == 0) logits_s[vg] = l + b1[vg];
    chunk++;
    if (chunk == 32) {
      __syncthreads();
      if (tid < 64) {
        float mx = -3.4e38f;
        #pragma unroll
        for (int i2 = 0; i2 < 4; ++i2) mx = fmaxf(mx, logits_s[tid * 4 + i2]);
        #pragma unroll
        for (int m = 1; m < 64; m <<= 1) mx = fmaxf(mx, __shfl_xor(mx, m, 64));
        float se = 0.f;
        #pragma unroll
        for (int i2 = 0; i2 < 4; ++i2) se += __expf(logits_s[tid * 4 + i2] - mx);
        #pragma unroll
        for (int m = 1; m < 64; m <<= 1) se += __shfl_xor(se, m, 64);
        if (tid == 0) {
          const float ly = logits_s[ys[b_g * T_ + ptau]];
          wg_loss += -(ly - mx - __logf(se));
        }
      }
      pending = 0;
      chunk = 0;
      __syncthreads();
    }
  };

  __syncthreads();

  for (int t = 0; t < T_; ++t) {
    // ---- 1. tag-poll stage of h(t-1): 8 x b64; tag = 2 LSBs of halfword 0 ----
    // word (b, wg') at hb[b*256+wg'] holds units wg'*4..+3 of batch b.
    const u64* hb = hg64 + (size_t)((t + 1) & 1) * WPS;
    const unsigned tagp = (unsigned)t & 3u;
    u64 v[8];
    for (;;) {
      bool ok = true;
      #pragma unroll
      for (int i = 0; i < 8; ++i) v[i] = agload64(&hb[i * NTH + tid]);
      #pragma unroll
      for (int i = 0; i < 8; ++i) ok &= (((unsigned)v[i] & 3u) == tagp);
      if (ok) break;
      __builtin_amdgcn_s_sleep(1);
    }
    #pragma unroll
    for (int i = 0; i < 8; ++i) {
      const unsigned lo = (unsigned)v[i], hi = (unsigned)(v[i] >> 32);
      float4 f;
      f.x = __builtin_bit_cast(float, (lo & 0xFFFCu) << 16);  // tag bits masked
      f.y = __builtin_bit_cast(float, lo & 0xFFFF0000u);
      f.z = __builtin_bit_cast(float, (hi & 0xFFFFu) << 16);
      f.w = __builtin_bit_cast(float, hi & 0xFFFF0000u);
      *(float4*)&hstage[i][tid * 4] = f;
    }
    if ((t & 31) == 0) {   // refresh 32-step Xs window
      const int b = tid >> 5, tt = t + (tid & 31);
      xw[b][tid & 31] = (tt < T_) ? Xs[b * T_ + tt] : 0;
    }
    __syncthreads();

    // ---- 2. gate partial dots: thread (row, seg), register-blocked over 8 batches ----
    float4 acc[8];
    #pragma unroll
    for (int b = 0; b < 8; ++b) acc[b] = make_float4(0.f, 0.f, 0.f, 0.f);
    #pragma unroll
    for (int q = 0; q < 16; ++q) {
      const int k0 = seg * 4 + q * 64;
      const float4 w = wreg[q];
      #pragma unroll
      for (int b = 0; b < 8; ++b) {
        const float4 h4 = *(const float4*)&hstage[b][k0];
        acc[b].x = fmaf(w.x, h4.x, acc[b].x);
        acc[b].y = fmaf(w.y, h4.y, acc[b].y);
        acc[b].z = fmaf(w.z, h4.z, acc[b].z);
        acc[b].w = fmaf(w.w, h4.w, acc[b].w);
      }
    }
    float s[8];
    #pragma unroll
    for (int b = 0; b < 8; ++b) s[b] = (acc[b].x + acc[b].y) + (acc[b].z + acc[b].w);
    #pragma unroll
    for (int m = 1; m < 16; m <<= 1) {
      #pragma unroll
      for (int b = 0; b < 8; ++b) s[b] += __shfl_xor(s[b], m, 64);
    }
    if (seg < 8)   // b = seg
      gates_s[row][seg] = s[seg] + Wis[row][xw[seg][t & 31]] + bias_s[row];
    __syncthreads();

    // ---- 3. c/h update + one u64 tagged store per batch (8 stores/WG) ----
    if (tid < 32) {
      const int jj = tid >> 3, b = tid & 7;
      float iv = gates_s[jj][b],      fv = gates_s[4 + jj][b];
      float gv = gates_s[8 + jj][b],  ov = gates_s[12 + jj][b];
      iv = 1.f / (1.f + __expf(-iv));
      fv = 1.f / (1.f + __expf(-fv));
      gv = tanhf(gv);
      ov = 1.f / (1.f + __expf(-ov));
      const float c = fv * c_s[jj][b] + iv * gv;
      c_s[jj][b] = c;
      const float h = ov * tanhf(c);
      // unit jj==0 carries the 2-bit tag in its bf16 LSBs (RNE to 4-ULP grid)
      const unsigned full = f2bf(h);
      const unsigned tagd = f2bf14(h) | ((unsigned)(t + 1) & 3u);
      const unsigned r16 = (jj == 0) ? tagd : full;
      const unsigned p1 = (unsigned)__shfl((int)r16, b + 8, 64);    // jj=1
      const unsigned p2 = (unsigned)__shfl((int)r16, b + 16, 64);   // jj=2
      const unsigned p3 = (unsigned)__shfl((int)r16, b + 24, 64);   // jj=3
      if (tid < 8) {
        const u64 w = (u64)r16 | ((u64)p1 << 16) | ((u64)p2 << 32) | ((u64)p3 << 48);
        agstore64(&hg64[(size_t)(t & 1) * WPS + tid * 256 + wg], w);
      }
    }

    // ---- 4. stash h(tau) for this WG's loss position ----
    const int tau = t - 1;   // hstage holds h(t-1)
    const bool newst = (tau >= 0 && (tau & 31) == slot && !pending);
    if (newst) {
      for (int i = tid; i < H_; i += NTH) stash[i] = hstage[b_g][i];
    }
    if (newst) { pending = 1; chunk = 0; ptau = tau; }
    __syncthreads();   // stash ready; also fences hstage reuse vs next stage

    // ---- 5. fused-loss slice: hides under h-store visibility window ----
    if (pending) do_chunk();
  }

  // ---- drain in-flight loss position ----
  while (pending) do_chunk();

  // ---- tau = T-1 (slot 31): poll-decode final h for batch b_g ----
  if (slot == 31) {
    const u64* hb = hg64 + (size_t)((T_ - 1) & 1) * WPS;
    u64 w;
    do { w = agload64(&hb[b_g * 256 + tid]); }
    while (((unsigned)w & 3u) != ((unsigned)T_ & 3u));
    const unsigned lo = (unsigned)w, hi = (unsigned)(w >> 32);
    float4 f;
    f.x = __builtin_bit_cast(float, (lo & 0xFFFCu) << 16);
    f.y = __builtin_bit_cast(float, lo & 0xFFFF0000u);
    f.z = __builtin_bit_cast(float, (hi & 0xFFFFu) << 16);
    f.w = __builtin_bit_cast(float, hi & 0xFFFF0000u);
    *(float4*)&stash[tid * 4] = f;
    pending = 1; chunk = 0; ptau = T_ - 1;
    __syncthreads();
    while (pending) do_chunk();
  }

  if (tid == 0) atomicAdd(out, wg_loss * (1.0f / (B_ * T_)));
}

extern "C" void kernel_launch(void* const* d_in, const int* in_sizes, int n_in,
                              void* d_out, int out_size, void* d_ws, size_t ws_size,
                              hipStream_t stream) {
  const int*   Xs   = (const int*)d_in[0];
  const int*   ys   = (const int*)d_in[1];
  // d_in[2] = predict (always 0)
  const float* W_ih = (const float*)d_in[3];
  const float* W_hh = (const float*)d_in[4];
  const float* b_ih = (const float*)d_in[5];
  const float* b_hh = (const float*)d_in[6];
  const float* W1   = (const float*)d_in[7];
  const float* b1   = (const float*)d_in[8];
  float* out = (float*)d_out;

  u64* hg64 = (u64*)d_ws;   // [2][WPS] tagged 64-bit words

  // replay-safe: zeroed buffer == h(-1)=0 with tag 0; zero loss accumulator
  hipMemsetAsync(d_out, 0, sizeof(float) * (size_t)out_size, stream);
  hipMemsetAsync(d_ws, 0, 2 * WPS * sizeof(u64), stream);

  void* args[] = { (void*)&Xs, (void*)&ys, (void*)&W_ih, (void*)&W_hh,
                   (void*)&b_ih, (void*)&b_hh, (void*)&W1, (void*)&b1,
                   (void*)&out, (void*)&hg64 };
  hipError_t e = hipLaunchCooperativeKernel((const void*)charrnn_lstm, dim3(NWG),
                                            dim3(NTH), args, 0, stream);
  if (e != hipSuccess) {
    hipLaunchKernelGGL(charrnn_lstm, dim3(NWG), dim3(NTH), 0, stream,
                       Xs, ys, W_ih, W_hh, b_ih, b_hh, W1, b1, out, hg64);
  }
}

// Round 7
// 8746.291 us; speedup vs baseline: 1.8679x; 1.0643x over previous
//
#include <hip/hip_runtime.h>

#define H_  1024
#define B_  8
#define T_  2048
#define V_  256
#define NWG 256
#define NTH 512
#define WPS (B_ * H_ / 4)   // 2048 u64 words per slot

typedef unsigned long long u64;

__device__ __forceinline__ u64 agload64(const u64* p) {
  return __hip_atomic_load(p, __ATOMIC_RELAXED, __HIP_MEMORY_SCOPE_AGENT);
}
__device__ __forceinline__ void agstore64(u64* p, u64 v) {
  __hip_atomic_store(p, v, __ATOMIC_RELAXED, __HIP_MEMORY_SCOPE_AGENT);
}
// full-precision bf16, RNE
__device__ __forceinline__ unsigned f2bf(float f) {
  unsigned u = __builtin_bit_cast(unsigned, f);
  return (u + 0x7fffu + ((u >> 16) & 1u)) >> 16;
}
// bf16 rounded (RNE) to 4-ULP grid: 2 LSBs free for the tag
__device__ __forceinline__ unsigned f2bf14(float f) {
  unsigned u = __builtin_bit_cast(unsigned, f);
  return ((u + 0x1FFFFu + ((u >> 18) & 1u)) >> 18) << 2;
}

__global__ __launch_bounds__(NTH, 1)
void charrnn_lstm(const int* __restrict__ Xs, const int* __restrict__ ys,
                  const float* __restrict__ W_ih, const float* __restrict__ W_hh,
                  const float* __restrict__ b_ih, const float* __restrict__ b_hh,
                  const float* __restrict__ W1, const float* __restrict__ b1,
                  float* __restrict__ out, u64* __restrict__ hg64)
{
  // 512 threads = 8 waves = 2 waves/SIMD (latency hiding in the dot phase).
  // LDS ~56 KB (<64KB). W_hh slice: 32 floats/thread = 8 float4 in VGPRs.
  __shared__ float hstage[B_][H_];
  __shared__ float Wis[16][V_];
  __shared__ float stash[H_];
  __shared__ float logits_s[V_];
  __shared__ float gates_s[16][8];
  __shared__ float c_s[4][8];
  __shared__ float bias_s[16];
  __shared__ int   xw[8][32];      // 32-step window of Xs

  const int wg   = blockIdx.x;
  const int tid  = threadIdx.x;
  const int b_g  = wg & 7;    // batch whose loss this WG computes
  const int slot = wg >> 3;   // t%32 slot this WG stashes
  const int row  = tid >> 5;  // 0..15 : local gate-row (gate*4 + jj)
  const int seg  = tid & 31;  // 0..31 : k-segment

  // ---- W_hh slice -> registers: thread (row,seg) holds 32 weights ----
  const int rg = (row >> 2) * H_ + wg * 4 + (row & 3);
  float4 wreg[8];
  #pragma unroll
  for (int q = 0; q < 8; ++q)
    wreg[q] = *(const float4*)&W_hh[(size_t)rg * H_ + seg * 4 + q * 128];

  // ---- one-time staging of W_ih slice into LDS ----
  for (int i = tid; i < 16 * (V_ / 4); i += NTH) {
    int rl = i >> 6;
    int kq = i & 63;
    int rr = (rl >> 2) * H_ + wg * 4 + (rl & 3);
    *(float4*)&Wis[rl][kq * 4] = *(const float4*)&W_ih[(size_t)rr * V_ + kq * 4];
  }
  if (tid < 16) {
    int rr = (tid >> 2) * H_ + wg * 4 + (tid & 3);
    bias_s[tid] = b_ih[rr] + b_hh[rr];
  }
  if (tid < 32) c_s[tid >> 3][tid & 7] = 0.f;

  int   pending = 0, chunk = 0, ptau = 0;
  float wg_loss = 0.f;

  auto do_chunk = [&]() {   // 1/32 slice of output-projection + CE for (b_g, ptau)
    const int v_loc = tid >> 6, lane64 = tid & 63;
    const int vg = chunk * 8 + v_loc;
    const float* wrow = &W1[(size_t)vg * H_];
    float4 la = make_float4(0.f, 0.f, 0.f, 0.f);
    #pragma unroll
    for (int j = 0; j < 4; ++j) {
      const int k0 = lane64 * 4 + j * 256;
      const float4 w4 = *(const float4*)&wrow[k0];
      const float4 h4 = *(const float4*)&stash[k0];
      la.x = fmaf(w4.x, h4.x, la.x);
      la.y = fmaf(w4.y, h4.y, la.y);
      la.z = fmaf(w4.z, h4.z, la.z);
      la.w = fmaf(w4.w, h4.w, la.w);
    }
    float l = (la.x + la.y) + (la.z + la.w);
    #pragma unroll
    for (int m = 1; m < 64; m <<= 1) l += __shfl_xor(l, m, 64);
    if (lane64 == 0) logits_s[vg] = l + b1[vg];
    chunk++;
    if (chunk == 32) {
      __syncthreads();
      if (tid < 64) {
        float mx = -3.4e38f;
        #pragma unroll
        for (int i2 = 0; i2 < 4; ++i2) mx = fmaxf(mx, logits_s[tid * 4 + i2]);
        #pragma unroll
        for (int m = 1; m < 64; m <<= 1) mx = fmaxf(mx, __shfl_xor(mx, m, 64));
        float se = 0.f;
        #pragma unroll
        for (int i2 = 0; i2 < 4; ++i2) se += __expf(logits_s[tid * 4 + i2] - mx);
        #pragma unroll
        for (int m = 1; m < 64; m <<= 1) se += __shfl_xor(se, m, 64);
        if (tid == 0) {
          const float ly = logits_s[ys[b_g * T_ + ptau]];
          wg_loss += -(ly - mx - __logf(se));
        }
      }
      pending = 0;
      chunk = 0;
      __syncthreads();
    }
  };

  __syncthreads();

  for (int t = 0; t < T_; ++t) {
    // ---- 1. tag-poll stage of h(t-1): 4 x b64; tag = 2 LSBs of halfword 0 ----
    const u64* hb = hg64 + (size_t)((t + 1) & 1) * WPS;
    const unsigned tagp = (unsigned)t & 3u;
    u64 v[4];
    for (;;) {
      bool ok = true;
      #pragma unroll
      for (int i = 0; i < 4; ++i) v[i] = agload64(&hb[i * NTH + tid]);
      #pragma unroll
      for (int i = 0; i < 4; ++i) ok &= (((unsigned)v[i] & 3u) == tagp);
      if (ok) break;
      __builtin_amdgcn_s_sleep(1);
    }
    #pragma unroll
    for (int i = 0; i < 4; ++i) {
      const int idx = i * NTH + tid;          // word index 0..2047
      const int b = idx >> 8, u4 = idx & 255; // word = (batch, 4-unit group)
      const unsigned lo = (unsigned)v[i], hi = (unsigned)(v[i] >> 32);
      float4 f;
      f.x = __builtin_bit_cast(float, (lo & 0xFFFCu) << 16);  // tag bits masked
      f.y = __builtin_bit_cast(float, lo & 0xFFFF0000u);
      f.z = __builtin_bit_cast(float, (hi & 0xFFFFu) << 16);
      f.w = __builtin_bit_cast(float, hi & 0xFFFF0000u);
      *(float4*)&hstage[b][u4 * 4] = f;
    }
    if ((t & 31) == 0 && tid < 256) {   // refresh 32-step Xs window
      const int b = tid >> 5, tt = t + (tid & 31);
      xw[b][tid & 31] = (tt < T_) ? Xs[b * T_ + tt] : 0;
    }
    __syncthreads();

    // ---- 2. gate partial dots: thread (row, seg), 8 q-iters x 8 batches ----
    float4 acc[8];
    #pragma unroll
    for (int b = 0; b < 8; ++b) acc[b] = make_float4(0.f, 0.f, 0.f, 0.f);
    #pragma unroll
    for (int q = 0; q < 8; ++q) {
      const int k0 = seg * 4 + q * 128;
      const float4 w = wreg[q];
      #pragma unroll
      for (int b = 0; b < 8; ++b) {
        const float4 h4 = *(const float4*)&hstage[b][k0];
        acc[b].x = fmaf(w.x, h4.x, acc[b].x);
        acc[b].y = fmaf(w.y, h4.y, acc[b].y);
        acc[b].z = fmaf(w.z, h4.z, acc[b].z);
        acc[b].w = fmaf(w.w, h4.w, acc[b].w);
      }
    }
    float s[8];
    #pragma unroll
    for (int b = 0; b < 8; ++b) s[b] = (acc[b].x + acc[b].y) + (acc[b].z + acc[b].w);
    #pragma unroll
    for (int m = 1; m < 32; m <<= 1) {
      #pragma unroll
      for (int b = 0; b < 8; ++b) s[b] += __shfl_xor(s[b], m, 64);
    }
    if (seg < 8)   // b = seg
      gates_s[row][seg] = s[seg] + Wis[row][xw[seg][t & 31]] + bias_s[row];
    __syncthreads();

    // ---- 3. c/h update + one u64 tagged store per batch (8 stores/WG) ----
    if (tid < 32) {
      const int jj = tid >> 3, b = tid & 7;
      float iv = gates_s[jj][b],      fv = gates_s[4 + jj][b];
      float gv = gates_s[8 + jj][b],  ov = gates_s[12 + jj][b];
      iv = 1.f / (1.f + __expf(-iv));
      fv = 1.f / (1.f + __expf(-fv));
      gv = tanhf(gv);
      ov = 1.f / (1.f + __expf(-ov));
      const float c = fv * c_s[jj][b] + iv * gv;
      c_s[jj][b] = c;
      const float h = ov * tanhf(c);
      // unit jj==0 carries the 2-bit tag in its bf16 LSBs (RNE to 4-ULP grid)
      const unsigned full = f2bf(h);
      const unsigned tagd = f2bf14(h) | ((unsigned)(t + 1) & 3u);
      const unsigned r16 = (jj == 0) ? tagd : full;
      const unsigned p1 = (unsigned)__shfl((int)r16, b + 8, 64);    // jj=1
      const unsigned p2 = (unsigned)__shfl((int)r16, b + 16, 64);   // jj=2
      const unsigned p3 = (unsigned)__shfl((int)r16, b + 24, 64);   // jj=3
      if (tid < 8) {
        const u64 w = (u64)r16 | ((u64)p1 << 16) | ((u64)p2 << 32) | ((u64)p3 << 48);
        agstore64(&hg64[(size_t)(t & 1) * WPS + tid * 256 + wg], w);
      }
    }

    // ---- 4. stash h(tau) for this WG's loss position ----
    const int tau = t - 1;   // hstage holds h(t-1)
    const bool newst = (tau >= 0 && (tau & 31) == slot && !pending);
    if (newst) {
      for (int i = tid; i < H_; i += NTH) stash[i] = hstage[b_g][i];
    }
    if (newst) { pending = 1; chunk = 0; ptau = tau; }
    __syncthreads();   // stash ready; also fences hstage reuse vs next stage

    // ---- 5. fused-loss slice: hides under h-store visibility window ----
    if (pending) do_chunk();
  }

  // ---- drain in-flight loss position ----
  while (pending) do_chunk();

  // ---- tau = T-1 (slot 31): poll-decode final h for batch b_g ----
  if (slot == 31) {
    const u64* hb = hg64 + (size_t)((T_ - 1) & 1) * WPS;
    if (tid < 256) {
      u64 w;
      do { w = agload64(&hb[b_g * 256 + tid]); }
      while (((unsigned)w & 3u) != ((unsigned)T_ & 3u));
      const unsigned lo = (unsigned)w, hi = (unsigned)(w >> 32);
      float4 f;
      f.x = __builtin_bit_cast(float, (lo & 0xFFFCu) << 16);
      f.y = __builtin_bit_cast(float, lo & 0xFFFF0000u);
      f.z = __builtin_bit_cast(float, (hi & 0xFFFFu) << 16);
      f.w = __builtin_bit_cast(float, hi & 0xFFFF0000u);
      *(float4*)&stash[tid * 4] = f;
    }
    pending = 1; chunk = 0; ptau = T_ - 1;
    __syncthreads();
    while (pending) do_chunk();
  }

  if (tid == 0) atomicAdd(out, wg_loss * (1.0f / (B_ * T_)));
}

extern "C" void kernel_launch(void* const* d_in, const int* in_sizes, int n_in,
                              void* d_out, int out_size, void* d_ws, size_t ws_size,
                              hipStream_t stream) {
  const int*   Xs   = (const int*)d_in[0];
  const int*   ys   = (const int*)d_in[1];
  // d_in[2] = predict (always 0)
  const float* W_ih = (const float*)d_in[3];
  const float* W_hh = (const float*)d_in[4];
  const float* b_ih = (const float*)d_in[5];
  const float* b_hh = (const float*)d_in[6];
  const float* W1   = (const float*)d_in[7];
  const float* b1   = (const float*)d_in[8];
  float* out = (float*)d_out;

  u64* hg64 = (u64*)d_ws;   // [2][WPS] tagged 64-bit words

  // replay-safe: zeroed buffer == h(-1)=0 with tag 0; zero loss accumulator
  hipMemsetAsync(d_out, 0, sizeof(float) * (size_t)out_size, stream);
  hipMemsetAsync(d_ws, 0, 2 * WPS * sizeof(u64), stream);

  void* args[] = { (void*)&Xs, (void*)&ys, (void*)&W_ih, (void*)&W_hh,
                   (void*)&b_ih, (void*)&b_hh, (void*)&W1, (void*)&b1,
                   (void*)&out, (void*)&hg64 };
  hipError_t e = hipLaunchCooperativeKernel((const void*)charrnn_lstm, dim3(NWG),
                                            dim3(NTH), args, 0, stream);
  if (e != hipSuccess) {
    hipLaunchKernelGGL(charrnn_lstm, dim3(NWG), dim3(NTH), 0, stream,
                       Xs, ys, W_ih, W_hh, b_ih, b_hh, W1, b1, out, hg64);
  }
}